// Round 5
// baseline (289.310 us; speedup 1.0000x reference)
//
#include <hip/hip_runtime.h>
#include <hip/hip_bf16.h>
#include <cstdint>
#include <cstddef>

// B=2, S=2048, D=1024, H=16, HD=64.  softmax over HEAD axis.
// v4b: same as v4 but __exp2f -> __builtin_amdgcn_exp2f (glibc macro clash).
// attn split 2x along k (grid 2048, 8 blocks/CU, fp16 partial O summed in the
// out-GEMM), den 2-head/64k tiles (grid 2048, 8 blocks/CU), qkv m97-style GEMM.

typedef __bf16 bf16x8 __attribute__((ext_vector_type(8)));
typedef __bf16 bf16x4 __attribute__((ext_vector_type(4)));
typedef _Float16 f16x4 __attribute__((ext_vector_type(4)));
typedef _Float16 f16x8 __attribute__((ext_vector_type(8)));
typedef float floatx4 __attribute__((ext_vector_type(4)));

#define S_LEN 2048
#define DIM 1024
#define NH 16
#define HD 64
#define MTOT 4096  // B * S
#define C_EXP 0.1803368801111244f  // log2(e)/8

__device__ __forceinline__ float fast_exp2(float x) { return __builtin_amdgcn_exp2f(x); }

__device__ __forceinline__ void g2l16(const void* g, void* l) {
    __builtin_amdgcn_global_load_lds(
        (const __attribute__((address_space(1))) void*)g,
        (__attribute__((address_space(3))) void*)l, 16, 0, 0);
}

// ---------------- cast fp32 -> bf16 (x) ----------------
__global__ void cast_f32_bf16(const float* __restrict__ s, __bf16* __restrict__ d, int n) {
    int i = (blockIdx.x * blockDim.x + threadIdx.x) * 4;
    if (i < n) {
        float4 v = *(const float4*)&s[i];
        bf16x4 o;
        o.x = (__bf16)v.x; o.y = (__bf16)v.y; o.z = (__bf16)v.z; o.w = (__bf16)v.w;
        *(bf16x4*)&d[i] = o;
    }
}

// ---------------- fused cast: Wq/Wk/Wv -> bf16, Wo -> f16 ----------------
__global__ void cast_w4(const float* __restrict__ w0, const float* __restrict__ w1,
                        const float* __restrict__ w2, const float* __restrict__ w3,
                        __bf16* __restrict__ o0, __bf16* __restrict__ o1,
                        __bf16* __restrict__ o2, _Float16* __restrict__ o3, int n) {
    int i = (blockIdx.x * blockDim.x + threadIdx.x) * 4;
    if (i >= n) return;
    if (blockIdx.y == 3) {
        float4 v = *(const float4*)&w3[i];
        f16x4 o;
        o[0] = (_Float16)v.x; o[1] = (_Float16)v.y; o[2] = (_Float16)v.z; o[3] = (_Float16)v.w;
        *(f16x4*)&o3[i] = o;
        return;
    }
    const float* s; __bf16* d;
    switch (blockIdx.y) {
        case 0: s = w0; d = o0; break;
        case 1: s = w1; d = o1; break;
        default: s = w2; d = o2; break;
    }
    float4 v = *(const float4*)&s[i];
    bf16x4 o;
    o.x = (__bf16)v.x; o.y = (__bf16)v.y; o.z = (__bf16)v.z; o.w = (__bf16)v.w;
    *(bf16x4*)&d[i] = o;
}

// ---------------- fused QKV projection GEMM (m97 structure) ----------------
// 128x128 tile, BK=32, grid (3072/128=24, 4096/128=32). Q,K bf16; V fp16 transposed.
__global__ __launch_bounds__(256, 2) void qkv_gemm(const __bf16* __restrict__ A,
                                                   const __bf16* __restrict__ Wq,
                                                   const __bf16* __restrict__ Wk,
                                                   const __bf16* __restrict__ Wv,
                                                   const float* __restrict__ bq,
                                                   const float* __restrict__ bk,
                                                   const float* __restrict__ bv,
                                                   __bf16* __restrict__ Qo,
                                                   __bf16* __restrict__ Ko,
                                                   _Float16* __restrict__ Vt) {
    const int tng = blockIdx.x * 128, tm = blockIdx.y * 128;
    const int wsel = tng >> 10, tn = tng & 1023;
    const __bf16* W = (wsel == 0) ? Wq : (wsel == 1) ? Wk : Wv;
    const float* bias = (wsel == 0) ? bq : (wsel == 1) ? bk : bv;
    __shared__ __bf16 As[128 * 32];  // 8 KB
    __shared__ __bf16 Bs[128 * 32];  // 8 KB
    const int tid = threadIdx.x, wid = tid >> 6, lane = tid & 63;
    const int l15 = lane & 15, quad = lane >> 4;
    const int wm = (wid >> 1) * 64, wn = (wid & 1) * 64;
    floatx4 acc[4][4] = {};
    for (int k0 = 0; k0 < DIM; k0 += 32) {
        __syncthreads();
#pragma unroll
        for (int i = 0; i < 2; ++i) {
            int slot = i * 256 + tid;  // 0..511
            int r = slot >> 2, c8 = (slot & 3) * 8;
            g2l16(&A[(size_t)(tm + r) * DIM + k0 + c8], &As[slot * 8]);
            g2l16(&W[(size_t)(tn + r) * DIM + k0 + c8], &Bs[slot * 8]);
        }
        __syncthreads();
        bf16x8 af[4], bf[4];
#pragma unroll
        for (int t = 0; t < 4; ++t) {
            af[t] = *(const bf16x8*)&As[(wm + t * 16 + l15) * 32 + quad * 8];
            bf[t] = *(const bf16x8*)&Bs[(wn + t * 16 + l15) * 32 + quad * 8];
        }
#pragma unroll
        for (int im = 0; im < 4; ++im)
#pragma unroll
            for (int in = 0; in < 4; ++in)
                acc[im][in] = __builtin_amdgcn_mfma_f32_16x16x32_bf16(af[im], bf[in], acc[im][in], 0, 0, 0);
    }
    if (wsel < 2) {
        __bf16* O = wsel ? Ko : Qo;
#pragma unroll
        for (int im = 0; im < 4; ++im)
#pragma unroll
            for (int in = 0; in < 4; ++in)
#pragma unroll
                for (int r = 0; r < 4; ++r) {
                    int row = tm + wm + im * 16 + quad * 4 + r;
                    int col = tn + wn + in * 16 + l15;
                    O[(size_t)row * DIM + col] = (__bf16)(acc[im][in][r] + bias[col]);
                }
    } else {
#pragma unroll
        for (int im = 0; im < 4; ++im)
#pragma unroll
            for (int in = 0; in < 4; ++in) {
                int cv = tn + wn + in * 16 + l15;
                int row4 = tm + wm + im * 16 + quad * 4;
                float bv_ = bias[cv];
                f16x4 o;
#pragma unroll
                for (int r = 0; r < 4; ++r) o[r] = (_Float16)(acc[im][in][r] + bv_);
                *(f16x4*)&Vt[(size_t)cv * MTOT + row4] = o;
            }
    }
}

// ---------------- pass 1: rd[b,q,k] = 1 / sum_h exp(s/8) ----------------
// tile 64q x 64k, 2 heads per barrier-pair, grid (32,32,2)=2048 -> 8 blocks/CU.
__global__ __launch_bounds__(256, 8) void den4(const __bf16* __restrict__ Q,
                                               const __bf16* __restrict__ Km,
                                               __bf16* __restrict__ rd) {
    const int kt = blockIdx.x * 64, qt = blockIdx.y * 64, b = blockIdx.z;
    __shared__ __bf16 Ks[2 * 2 * 64 * 32];  // 16 KB: [hs][panel][tok][32]
    const int tid = threadIdx.x, wid = tid >> 6, lane = tid & 63;
    const int l15 = lane & 15, quad = lane >> 4;
    const int wq = wid * 16;
    floatx4 dsum[4] = {};
    const size_t qrow = (size_t)(b * S_LEN + qt + wq + l15) * DIM;
    for (int hh = 0; hh < 8; ++hh) {
        __syncthreads();
#pragma unroll
        for (int i = 0; i < 4; ++i) {
            int slot = i * 256 + tid;  // 0..1023
            int hs = slot >> 9, rem = slot & 511;
            int p = rem >> 8, rem2 = rem & 255;
            int r = rem2 >> 2, c8 = (rem2 & 3) * 8;
            g2l16(&Km[(size_t)(b * S_LEN + kt + r) * DIM + (hh * 2 + hs) * HD + p * 32 + c8],
                  &Ks[slot * 8]);
        }
        __syncthreads();
#pragma unroll
        for (int hs = 0; hs < 2; ++hs) {
            int h = hh * 2 + hs;
            bf16x8 af0 = *(const bf16x8*)&Q[qrow + h * HD + quad * 8];
            bf16x8 af1 = *(const bf16x8*)&Q[qrow + h * HD + 32 + quad * 8];
#pragma unroll
            for (int n = 0; n < 4; ++n) {
                bf16x8 b0 = *(const bf16x8*)&Ks[hs * 4096 + (n * 16 + l15) * 32 + quad * 8];
                bf16x8 b1 = *(const bf16x8*)&Ks[hs * 4096 + 2048 + (n * 16 + l15) * 32 + quad * 8];
                floatx4 acc = {};
                acc = __builtin_amdgcn_mfma_f32_16x16x32_bf16(af0, b0, acc, 0, 0, 0);
                acc = __builtin_amdgcn_mfma_f32_16x16x32_bf16(af1, b1, acc, 0, 0, 0);
#pragma unroll
                for (int r = 0; r < 4; ++r) dsum[n][r] += fast_exp2(acc[r] * C_EXP);
            }
        }
    }
#pragma unroll
    for (int n = 0; n < 4; ++n)
#pragma unroll
        for (int r = 0; r < 4; ++r) {
            int q = qt + wq + quad * 4 + r;
            int k = kt + n * 16 + l15;
            rd[(size_t)(b * S_LEN + q) * S_LEN + k] = (__bf16)(1.0f / dsum[n][r]);
        }
}

// ---------------- pass 2: partial AO = sum_{k in half} (exp(s/8)*rd) * V ----------------
// q-tile 64, k-tile 64, k-range split in 2 -> grid (64,16,2), 8 blocks/CU.
__global__ __launch_bounds__(256, 8) void attn4(const __bf16* __restrict__ Q,
                                                const __bf16* __restrict__ Km,
                                                const _Float16* __restrict__ Vt,
                                                const __bf16* __restrict__ rd,
                                                _Float16* __restrict__ AO1,
                                                _Float16* __restrict__ AO2) {
    const int qt = (blockIdx.x >> 1) * 64, ks = blockIdx.x & 1;
    const int h = blockIdx.y, b = blockIdx.z;
    __shared__ __bf16 Ks[2 * 64 * 32];   // 8 KB panels
    __shared__ _Float16 Vts[64 * 72];    // 9 KB padded [d][ktok]
    const int tid = threadIdx.x, wid = tid >> 6, lane = tid & 63;
    const int l15 = lane & 15, quad = lane >> 4;
    const int wq = wid * 16;
    const size_t qrow = (size_t)(b * S_LEN + qt + wq + l15) * DIM + h * HD;
    bf16x8 qf0 = *(const bf16x8*)&Q[qrow + quad * 8];
    bf16x8 qf1 = *(const bf16x8*)&Q[qrow + 32 + quad * 8];
    const __bf16* rdrow = &rd[(size_t)(b * S_LEN + qt + wq + l15) * S_LEN];
    floatx4 oacc[4] = {};
    const int kt0 = ks * (S_LEN / 2), kt1 = kt0 + S_LEN / 2;
    for (int kt = kt0; kt < kt1; kt += 64) {
        __syncthreads();
#pragma unroll
        for (int i = 0; i < 2; ++i) {
            int slot = i * 256 + tid;  // 0..511
            int p = slot >> 8, rem = slot & 255;
            int r = rem >> 2, c8 = (rem & 3) * 8;
            g2l16(&Km[(size_t)(b * S_LEN + kt + r) * DIM + h * HD + p * 32 + c8], &Ks[slot * 8]);
        }
#pragma unroll
        for (int i = 0; i < 2; ++i) {
            int slot = i * 256 + tid;  // 0..511
            int r = slot >> 3, c = (slot & 7) * 8;
            *(f16x8*)&Vts[r * 72 + c] =
                *(const f16x8*)&Vt[(size_t)(h * HD + r) * MTOT + b * S_LEN + kt + c];
        }
        __syncthreads();
#pragma unroll
        for (int mp = 0; mp < 4; ++mp) {
            bf16x8 kf0 = *(const bf16x8*)&Ks[(mp * 16 + l15) * 32 + quad * 8];
            bf16x8 kf1 = *(const bf16x8*)&Ks[2048 + (mp * 16 + l15) * 32 + quad * 8];
            floatx4 s = {};
            s = __builtin_amdgcn_mfma_f32_16x16x32_bf16(kf0, qf0, s, 0, 0, 0);
            s = __builtin_amdgcn_mfma_f32_16x16x32_bf16(kf1, qf1, s, 0, 0, 0);
            bf16x4 rv = *(const bf16x4*)&rdrow[kt + mp * 16 + quad * 4];
            f16x4 pa;
#pragma unroll
            for (int r = 0; r < 4; ++r)
                pa[r] = (_Float16)(fast_exp2(s[r] * C_EXP) * (float)rv[r]);
#pragma unroll
            for (int n = 0; n < 4; ++n) {
                f16x4 vb = *(const f16x4*)&Vts[(n * 16 + l15) * 72 + mp * 16 + quad * 4];
                oacc[n] = __builtin_amdgcn_mfma_f32_16x16x16f16(pa, vb, oacc[n], 0, 0, 0);
            }
        }
    }
    _Float16* AO = ks ? AO2 : AO1;
#pragma unroll
    for (int n = 0; n < 4; ++n)
#pragma unroll
        for (int r = 0; r < 4; ++r) {
            int row = qt + wq + quad * 4 + r;
            int col = h * HD + n * 16 + l15;
            AO[(size_t)(b * S_LEN + row) * DIM + col] = (_Float16)oacc[n][r];
        }
}

// ---------------- output projection: C = (AO1+AO2) @ Wo^T + bo, fp32 out ----------------
// f16 MFMA, 128M x 64N, BK=64, grid (16,32)=512.
__global__ __launch_bounds__(256, 2) void gemm_out2(const _Float16* __restrict__ A1,
                                                    const _Float16* __restrict__ A2,
                                                    const _Float16* __restrict__ Bw,
                                                    const float* __restrict__ bias,
                                                    float* __restrict__ C) {
    const int tm = blockIdx.y * 128, tn = blockIdx.x * 64;
    __shared__ _Float16 As1[2 * 128 * 32];  // 16 KB
    __shared__ _Float16 As2[2 * 128 * 32];  // 16 KB
    __shared__ _Float16 Bs[2 * 64 * 32];    // 8 KB
    const int tid = threadIdx.x, wid = tid >> 6, lane = tid & 63;
    const int l15 = lane & 15, quad = lane >> 4;
    const int wm = (wid >> 1) * 64, wn = (wid & 1) * 32;
    floatx4 acc[4][2] = {};
    for (int k0 = 0; k0 < DIM; k0 += 64) {
        __syncthreads();
#pragma unroll
        for (int i = 0; i < 4; ++i) {
            int slot = i * 256 + tid;  // 0..1023
            int p = slot >> 9, rem = slot & 511;
            int r = rem >> 2, c8 = (rem & 3) * 8;
            size_t ga = (size_t)(tm + r) * DIM + k0 + p * 32 + c8;
            g2l16(&A1[ga], &As1[slot * 8]);
            g2l16(&A2[ga], &As2[slot * 8]);
        }
#pragma unroll
        for (int i = 0; i < 2; ++i) {
            int slot = i * 256 + tid;  // 0..511
            int p = slot >> 8, rem = slot & 255;
            int r = rem >> 2, c8 = (rem & 3) * 8;
            g2l16(&Bw[(size_t)(tn + r) * DIM + k0 + p * 32 + c8], &Bs[slot * 8]);
        }
        __syncthreads();
#pragma unroll
        for (int kc = 0; kc < 2; ++kc) {
            f16x8 af[4], bf[2];
#pragma unroll
            for (int t = 0; t < 4; ++t) {
                int off = kc * 4096 + (wm + t * 16 + l15) * 32 + quad * 8;
                f16x8 a1 = *(const f16x8*)&As1[off];
                f16x8 a2 = *(const f16x8*)&As2[off];
                af[t] = a1 + a2;
            }
#pragma unroll
            for (int t = 0; t < 2; ++t)
                bf[t] = *(const f16x8*)&Bs[kc * 2048 + (wn + t * 16 + l15) * 32 + quad * 8];
#pragma unroll
            for (int im = 0; im < 4; ++im)
#pragma unroll
                for (int in = 0; in < 2; ++in)
                    acc[im][in] = __builtin_amdgcn_mfma_f32_16x16x32_f16(af[im], bf[in], acc[im][in], 0, 0, 0);
        }
    }
#pragma unroll
    for (int im = 0; im < 4; ++im)
#pragma unroll
        for (int in = 0; in < 2; ++in)
#pragma unroll
            for (int r = 0; r < 4; ++r) {
                int row = tm + wm + im * 16 + quad * 4 + r;
                int col = tn + wn + in * 16 + l15;
                C[(size_t)row * DIM + col] = acc[im][in][r] + bias[col];
            }
}

extern "C" void kernel_launch(void* const* d_in, const int* in_sizes, int n_in,
                              void* d_out, int out_size, void* d_ws, size_t ws_size,
                              hipStream_t stream) {
    const float* x  = (const float*)d_in[0];
    const float* Wq = (const float*)d_in[1];
    const float* bq = (const float*)d_in[2];
    const float* Wk = (const float*)d_in[3];
    const float* bk = (const float*)d_in[4];
    const float* Wv = (const float*)d_in[5];
    const float* bv = (const float*)d_in[6];
    const float* Wo = (const float*)d_in[7];
    const float* bo = (const float*)d_in[8];
    float* out = (float*)d_out;

    char* ws = (char*)d_ws;
    const size_t MB = 1u << 20;
    __bf16*    xb  = (__bf16*)(ws);              // 8 MB
    __bf16*    Wqb = (__bf16*)(ws + 8 * MB);     // 2 MB each
    __bf16*    Wkb = (__bf16*)(ws + 10 * MB);
    __bf16*    Wvb = (__bf16*)(ws + 12 * MB);
    _Float16*  Wof = (_Float16*)(ws + 14 * MB);
    __bf16*    Qb  = (__bf16*)(ws + 16 * MB);    // 8 MB
    __bf16*    Kb  = (__bf16*)(ws + 24 * MB);    // 8 MB
    _Float16*  VtH = (_Float16*)(ws + 32 * MB);  // 8 MB
    __bf16*    rd  = (__bf16*)(ws + 40 * MB);    // 16 MB
    _Float16*  AO1 = (_Float16*)(ws + 56 * MB);  // 8 MB
    _Float16*  AO2 = (_Float16*)(ws + 64 * MB);  // 8 MB (total 72 MB)

    cast_f32_bf16<<<4096, 256, 0, stream>>>(x, xb, MTOT * DIM);
    cast_w4<<<dim3(1024, 4), 256, 0, stream>>>(Wq, Wk, Wv, Wo, Wqb, Wkb, Wvb, Wof, DIM * DIM);

    qkv_gemm<<<dim3(24, 32), 256, 0, stream>>>(xb, Wqb, Wkb, Wvb, bq, bk, bv, Qb, Kb, VtH);

    den4<<<dim3(S_LEN / 64, S_LEN / 64, 2), 256, 0, stream>>>(Qb, Kb, rd);

    attn4<<<dim3((S_LEN / 64) * 2, NH, 2), 256, 0, stream>>>(Qb, Kb, VtH, rd, AO1, AO2);

    gemm_out2<<<dim3(DIM / 64, MTOT / 128), 256, 0, stream>>>(AO1, AO2, Wof, bo, out);
}

// Round 6
// 277.499 us; speedup vs baseline: 1.0426x; 1.0426x over previous
//
#include <hip/hip_runtime.h>
#include <hip/hip_bf16.h>
#include <cstdint>
#include <cstddef>

// B=2, S=2048, D=1024, H=16, HD=64.  softmax over HEAD axis.
// v6: single-barrier double-buffered k-loops in attn/den (stage(next) issued
// before compute(cur); rd/Q frag loads hoisted ahead of stage so their vmcnt
// waits don't drain staging). attn wave-tile widened to 32q (8 acc chains).

typedef __bf16 bf16x8 __attribute__((ext_vector_type(8)));
typedef __bf16 bf16x4 __attribute__((ext_vector_type(4)));
typedef _Float16 f16x4 __attribute__((ext_vector_type(4)));
typedef _Float16 f16x8 __attribute__((ext_vector_type(8)));
typedef float floatx4 __attribute__((ext_vector_type(4)));

#define S_LEN 2048
#define DIM 1024
#define NH 16
#define HD 64
#define MTOT 4096  // B * S
#define C_EXP 0.1803368801111244f  // log2(e)/8

__device__ __forceinline__ float fast_exp2(float x) { return __builtin_amdgcn_exp2f(x); }

__device__ __forceinline__ void g2l16(const void* g, void* l) {
    __builtin_amdgcn_global_load_lds(
        (const __attribute__((address_space(1))) void*)g,
        (__attribute__((address_space(3))) void*)l, 16, 0, 0);
}

// ---------------- cast fp32 -> bf16 (x) ----------------
__global__ void cast_f32_bf16(const float* __restrict__ s, __bf16* __restrict__ d, int n) {
    int i = (blockIdx.x * blockDim.x + threadIdx.x) * 4;
    if (i < n) {
        float4 v = *(const float4*)&s[i];
        bf16x4 o;
        o.x = (__bf16)v.x; o.y = (__bf16)v.y; o.z = (__bf16)v.z; o.w = (__bf16)v.w;
        *(bf16x4*)&d[i] = o;
    }
}

// ---------------- fused cast: Wq/Wk/Wv -> bf16, Wo -> f16 ----------------
__global__ void cast_w4(const float* __restrict__ w0, const float* __restrict__ w1,
                        const float* __restrict__ w2, const float* __restrict__ w3,
                        __bf16* __restrict__ o0, __bf16* __restrict__ o1,
                        __bf16* __restrict__ o2, _Float16* __restrict__ o3, int n) {
    int i = (blockIdx.x * blockDim.x + threadIdx.x) * 4;
    if (i >= n) return;
    if (blockIdx.y == 3) {
        float4 v = *(const float4*)&w3[i];
        f16x4 o;
        o[0] = (_Float16)v.x; o[1] = (_Float16)v.y; o[2] = (_Float16)v.z; o[3] = (_Float16)v.w;
        *(f16x4*)&o3[i] = o;
        return;
    }
    const float* s; __bf16* d;
    switch (blockIdx.y) {
        case 0: s = w0; d = o0; break;
        case 1: s = w1; d = o1; break;
        default: s = w2; d = o2; break;
    }
    float4 v = *(const float4*)&s[i];
    bf16x4 o;
    o.x = (__bf16)v.x; o.y = (__bf16)v.y; o.z = (__bf16)v.z; o.w = (__bf16)v.w;
    *(bf16x4*)&d[i] = o;
}

// ---------------- fused QKV projection GEMM (m97 structure) ----------------
__global__ __launch_bounds__(256, 2) void qkv_gemm(const __bf16* __restrict__ A,
                                                   const __bf16* __restrict__ Wq,
                                                   const __bf16* __restrict__ Wk,
                                                   const __bf16* __restrict__ Wv,
                                                   const float* __restrict__ bq,
                                                   const float* __restrict__ bk,
                                                   const float* __restrict__ bv,
                                                   __bf16* __restrict__ Qo,
                                                   __bf16* __restrict__ Ko,
                                                   _Float16* __restrict__ Vt) {
    const int tng = blockIdx.x * 128, tm = blockIdx.y * 128;
    const int wsel = tng >> 10, tn = tng & 1023;
    const __bf16* W = (wsel == 0) ? Wq : (wsel == 1) ? Wk : Wv;
    const float* bias = (wsel == 0) ? bq : (wsel == 1) ? bk : bv;
    __shared__ __bf16 As[128 * 32];
    __shared__ __bf16 Bs[128 * 32];
    const int tid = threadIdx.x, wid = tid >> 6, lane = tid & 63;
    const int l15 = lane & 15, quad = lane >> 4;
    const int wm = (wid >> 1) * 64, wn = (wid & 1) * 64;
    floatx4 acc[4][4] = {};
    for (int k0 = 0; k0 < DIM; k0 += 32) {
        __syncthreads();
#pragma unroll
        for (int i = 0; i < 2; ++i) {
            int slot = i * 256 + tid;
            int r = slot >> 2, c8 = (slot & 3) * 8;
            g2l16(&A[(size_t)(tm + r) * DIM + k0 + c8], &As[slot * 8]);
            g2l16(&W[(size_t)(tn + r) * DIM + k0 + c8], &Bs[slot * 8]);
        }
        __syncthreads();
        bf16x8 af[4], bf[4];
#pragma unroll
        for (int t = 0; t < 4; ++t) {
            af[t] = *(const bf16x8*)&As[(wm + t * 16 + l15) * 32 + quad * 8];
            bf[t] = *(const bf16x8*)&Bs[(wn + t * 16 + l15) * 32 + quad * 8];
        }
#pragma unroll
        for (int im = 0; im < 4; ++im)
#pragma unroll
            for (int in = 0; in < 4; ++in)
                acc[im][in] = __builtin_amdgcn_mfma_f32_16x16x32_bf16(af[im], bf[in], acc[im][in], 0, 0, 0);
    }
    if (wsel < 2) {
        __bf16* O = wsel ? Ko : Qo;
#pragma unroll
        for (int im = 0; im < 4; ++im)
#pragma unroll
            for (int in = 0; in < 4; ++in)
#pragma unroll
                for (int r = 0; r < 4; ++r) {
                    int row = tm + wm + im * 16 + quad * 4 + r;
                    int col = tn + wn + in * 16 + l15;
                    O[(size_t)row * DIM + col] = (__bf16)(acc[im][in][r] + bias[col]);
                }
    } else {
#pragma unroll
        for (int im = 0; im < 4; ++im)
#pragma unroll
            for (int in = 0; in < 4; ++in) {
                int cv = tn + wn + in * 16 + l15;
                int row4 = tm + wm + im * 16 + quad * 4;
                float bv_ = bias[cv];
                f16x4 o;
#pragma unroll
                for (int r = 0; r < 4; ++r) o[r] = (_Float16)(acc[im][in][r] + bv_);
                *(f16x4*)&Vt[(size_t)cv * MTOT + row4] = o;
            }
    }
}

// ---------------- pass 1: rd = 1/sum_h exp(s/8), dbuf single-barrier ----------------
// tile 64q x 64k, 2 heads per iter, double-buffered K staging. grid (32,32,2).
__global__ __launch_bounds__(256, 4) void den6(const __bf16* __restrict__ Q,
                                               const __bf16* __restrict__ Km,
                                               __bf16* __restrict__ rd) {
    const int kt = blockIdx.x * 64, qt = blockIdx.y * 64, b = blockIdx.z;
    __shared__ __bf16 Ks[2][2 * 2 * 64 * 32];  // 2 bufs x 16 KB
    const int tid = threadIdx.x, wid = tid >> 6, lane = tid & 63;
    const int l15 = lane & 15, quad = lane >> 4;
    const int wq = wid * 16;
    floatx4 dsum[4] = {};
    const size_t qrow = (size_t)(b * S_LEN + qt + wq + l15) * DIM;
    const size_t kbase = (size_t)(b * S_LEN + kt) * DIM;

    // prologue: stage hh=0 into buf 0
#pragma unroll
    for (int i = 0; i < 4; ++i) {
        int slot = i * 256 + tid;
        int hs = slot >> 9, rem = slot & 511;
        int p = rem >> 8, rem2 = rem & 255;
        int r = rem2 >> 2, c8 = (rem2 & 3) * 8;
        g2l16(&Km[kbase + (size_t)r * DIM + hs * HD + p * 32 + c8], &Ks[0][slot * 8]);
    }
    for (int hh = 0; hh < 8; ++hh) {
        const int cur = hh & 1, nxt = cur ^ 1;
        __syncthreads();  // buf[cur] ready; buf[nxt] free
        // Q frags for this iter's 2 heads (issued BEFORE next stage -> older in vmcnt FIFO)
        bf16x8 af[2][2];
#pragma unroll
        for (int hs = 0; hs < 2; ++hs) {
            af[hs][0] = *(const bf16x8*)&Q[qrow + (hh * 2 + hs) * HD + quad * 8];
            af[hs][1] = *(const bf16x8*)&Q[qrow + (hh * 2 + hs) * HD + 32 + quad * 8];
        }
        if (hh + 1 < 8) {
#pragma unroll
            for (int i = 0; i < 4; ++i) {
                int slot = i * 256 + tid;
                int hs = slot >> 9, rem = slot & 511;
                int p = rem >> 8, rem2 = rem & 255;
                int r = rem2 >> 2, c8 = (rem2 & 3) * 8;
                g2l16(&Km[kbase + (size_t)r * DIM + ((hh + 1) * 2 + hs) * HD + p * 32 + c8],
                      &Ks[nxt][slot * 8]);
            }
        }
#pragma unroll
        for (int hs = 0; hs < 2; ++hs) {
#pragma unroll
            for (int n = 0; n < 4; ++n) {
                bf16x8 b0 = *(const bf16x8*)&Ks[cur][hs * 4096 + (n * 16 + l15) * 32 + quad * 8];
                bf16x8 b1 = *(const bf16x8*)&Ks[cur][hs * 4096 + 2048 + (n * 16 + l15) * 32 + quad * 8];
                floatx4 acc = {};
                acc = __builtin_amdgcn_mfma_f32_16x16x32_bf16(af[hs][0], b0, acc, 0, 0, 0);
                acc = __builtin_amdgcn_mfma_f32_16x16x32_bf16(af[hs][1], b1, acc, 0, 0, 0);
#pragma unroll
                for (int r = 0; r < 4; ++r) dsum[n][r] += fast_exp2(acc[r] * C_EXP);
            }
        }
    }
#pragma unroll
    for (int n = 0; n < 4; ++n)
#pragma unroll
        for (int r = 0; r < 4; ++r) {
            int q = qt + wq + quad * 4 + r;
            int k = kt + n * 16 + l15;
            rd[(size_t)(b * S_LEN + q) * S_LEN + k] = (__bf16)(1.0f / dsum[n][r]);
        }
}

// ---------------- pass 2: partial AO, dbuf single-barrier, 32q/wave ----------------
// q-tile 128/block, k-tile 64, k-split 2 -> grid (32,16,2)=1024, 4 blocks/CU.
__global__ __launch_bounds__(256, 4) void attn6(const __bf16* __restrict__ Q,
                                                const __bf16* __restrict__ Km,
                                                const _Float16* __restrict__ Vt,
                                                const __bf16* __restrict__ rd,
                                                _Float16* __restrict__ AO1,
                                                _Float16* __restrict__ AO2) {
    const int qt = (blockIdx.x >> 1) * 128, ks = blockIdx.x & 1;
    const int h = blockIdx.y, b = blockIdx.z;
    __shared__ __bf16 Ks[2][2 * 64 * 32];   // 2 bufs x 8 KB, panels [p][tok][32]
    __shared__ _Float16 Vts[2][64 * 72];    // 2 bufs x 9 KB, padded [d][ktok]
    const int tid = threadIdx.x, wid = tid >> 6, lane = tid & 63;
    const int l15 = lane & 15, quad = lane >> 4;
    const int wq = wid * 32;
    const size_t qrow0 = (size_t)(b * S_LEN + qt + wq + l15) * DIM + h * HD;
    const size_t qrow1 = qrow0 + 16 * DIM;
    bf16x8 qf[2][2];
    qf[0][0] = *(const bf16x8*)&Q[qrow0 + quad * 8];
    qf[0][1] = *(const bf16x8*)&Q[qrow0 + 32 + quad * 8];
    qf[1][0] = *(const bf16x8*)&Q[qrow1 + quad * 8];
    qf[1][1] = *(const bf16x8*)&Q[qrow1 + 32 + quad * 8];
    const __bf16* rdrow0 = &rd[(size_t)(b * S_LEN + qt + wq + l15) * S_LEN];
    const __bf16* rdrow1 = rdrow0 + (size_t)16 * S_LEN;
    floatx4 oacc[2][4] = {};
    const int kt0 = ks * (S_LEN / 2);
    const size_t kdim = (size_t)b * S_LEN * DIM;

    // prologue: stage kt0 into buf 0  (V global loads first, then K g2l16)
    {
        f16x8 vtmp[2];
#pragma unroll
        for (int i = 0; i < 2; ++i) {
            int slot = i * 256 + tid;
            int r = slot >> 3, c = (slot & 7) * 8;
            vtmp[i] = *(const f16x8*)&Vt[(size_t)(h * HD + r) * MTOT + b * S_LEN + kt0 + c];
        }
#pragma unroll
        for (int i = 0; i < 2; ++i) {
            int slot = i * 256 + tid;
            int p = slot >> 8, rem = slot & 255;
            int r = rem >> 2, c8 = (rem & 3) * 8;
            g2l16(&Km[kdim + (size_t)(kt0 + r) * DIM + h * HD + p * 32 + c8], &Ks[0][slot * 8]);
        }
#pragma unroll
        for (int i = 0; i < 2; ++i) {
            int slot = i * 256 + tid;
            int r = slot >> 3, c = (slot & 7) * 8;
            *(f16x8*)&Vts[0][r * 72 + c] = vtmp[i];
        }
    }
    for (int it = 0; it < 16; ++it) {
        const int cur = it & 1, nxt = cur ^ 1;
        const int kt = kt0 + it * 64;
        __syncthreads();
        // rd prefetch for this iter (oldest in vmcnt FIFO)
        bf16x4 rv[2][4];
#pragma unroll
        for (int mp = 0; mp < 4; ++mp) {
            rv[0][mp] = *(const bf16x4*)&rdrow0[kt + mp * 16 + quad * 4];
            rv[1][mp] = *(const bf16x4*)&rdrow1[kt + mp * 16 + quad * 4];
        }
        // stage next tile
        if (it + 1 < 16) {
            const int ktn = kt + 64;
            f16x8 vtmp[2];
#pragma unroll
            for (int i = 0; i < 2; ++i) {
                int slot = i * 256 + tid;
                int r = slot >> 3, c = (slot & 7) * 8;
                vtmp[i] = *(const f16x8*)&Vt[(size_t)(h * HD + r) * MTOT + b * S_LEN + ktn + c];
            }
#pragma unroll
            for (int i = 0; i < 2; ++i) {
                int slot = i * 256 + tid;
                int p = slot >> 8, rem = slot & 255;
                int r = rem >> 2, c8 = (rem & 3) * 8;
                g2l16(&Km[kdim + (size_t)(ktn + r) * DIM + h * HD + p * 32 + c8], &Ks[nxt][slot * 8]);
            }
#pragma unroll
            for (int i = 0; i < 2; ++i) {
                int slot = i * 256 + tid;
                int r = slot >> 3, c = (slot & 7) * 8;
                *(f16x8*)&Vts[nxt][r * 72 + c] = vtmp[i];
            }
        }
        // compute current tile
#pragma unroll
        for (int mp = 0; mp < 4; ++mp) {
            bf16x8 kf0 = *(const bf16x8*)&Ks[cur][(mp * 16 + l15) * 32 + quad * 8];
            bf16x8 kf1 = *(const bf16x8*)&Ks[cur][2048 + (mp * 16 + l15) * 32 + quad * 8];
            floatx4 s0 = {}, s1 = {};
            s0 = __builtin_amdgcn_mfma_f32_16x16x32_bf16(kf0, qf[0][0], s0, 0, 0, 0);
            s0 = __builtin_amdgcn_mfma_f32_16x16x32_bf16(kf1, qf[0][1], s0, 0, 0, 0);
            s1 = __builtin_amdgcn_mfma_f32_16x16x32_bf16(kf0, qf[1][0], s1, 0, 0, 0);
            s1 = __builtin_amdgcn_mfma_f32_16x16x32_bf16(kf1, qf[1][1], s1, 0, 0, 0);
            f16x4 pa0, pa1;
#pragma unroll
            for (int r = 0; r < 4; ++r) {
                pa0[r] = (_Float16)(fast_exp2(s0[r] * C_EXP) * (float)rv[0][mp][r]);
                pa1[r] = (_Float16)(fast_exp2(s1[r] * C_EXP) * (float)rv[1][mp][r]);
            }
#pragma unroll
            for (int n = 0; n < 4; ++n) {
                f16x4 vb = *(const f16x4*)&Vts[cur][(n * 16 + l15) * 72 + mp * 16 + quad * 4];
                oacc[0][n] = __builtin_amdgcn_mfma_f32_16x16x16f16(pa0, vb, oacc[0][n], 0, 0, 0);
                oacc[1][n] = __builtin_amdgcn_mfma_f32_16x16x16f16(pa1, vb, oacc[1][n], 0, 0, 0);
            }
        }
    }
    _Float16* AO = ks ? AO2 : AO1;
#pragma unroll
    for (int np = 0; np < 2; ++np)
#pragma unroll
        for (int n = 0; n < 4; ++n)
#pragma unroll
            for (int r = 0; r < 4; ++r) {
                int row = qt + wq + np * 16 + quad * 4 + r;
                int col = h * HD + n * 16 + l15;
                AO[(size_t)(b * S_LEN + row) * DIM + col] = (_Float16)oacc[np][n][r];
            }
}

// ---------------- output projection: C = (AO1+AO2) @ Wo^T + bo ----------------
__global__ __launch_bounds__(256, 2) void gemm_out2(const _Float16* __restrict__ A1,
                                                    const _Float16* __restrict__ A2,
                                                    const _Float16* __restrict__ Bw,
                                                    const float* __restrict__ bias,
                                                    float* __restrict__ C) {
    const int tm = blockIdx.y * 128, tn = blockIdx.x * 64;
    __shared__ _Float16 As1[2 * 128 * 32];
    __shared__ _Float16 As2[2 * 128 * 32];
    __shared__ _Float16 Bs[2 * 64 * 32];
    const int tid = threadIdx.x, wid = tid >> 6, lane = tid & 63;
    const int l15 = lane & 15, quad = lane >> 4;
    const int wm = (wid >> 1) * 64, wn = (wid & 1) * 32;
    floatx4 acc[4][2] = {};
    for (int k0 = 0; k0 < DIM; k0 += 64) {
        __syncthreads();
#pragma unroll
        for (int i = 0; i < 4; ++i) {
            int slot = i * 256 + tid;
            int p = slot >> 9, rem = slot & 511;
            int r = rem >> 2, c8 = (rem & 3) * 8;
            size_t ga = (size_t)(tm + r) * DIM + k0 + p * 32 + c8;
            g2l16(&A1[ga], &As1[slot * 8]);
            g2l16(&A2[ga], &As2[slot * 8]);
        }
#pragma unroll
        for (int i = 0; i < 2; ++i) {
            int slot = i * 256 + tid;
            int p = slot >> 8, rem = slot & 255;
            int r = rem >> 2, c8 = (rem & 3) * 8;
            g2l16(&Bw[(size_t)(tn + r) * DIM + k0 + p * 32 + c8], &Bs[slot * 8]);
        }
        __syncthreads();
#pragma unroll
        for (int kc = 0; kc < 2; ++kc) {
            f16x8 af[4], bf[2];
#pragma unroll
            for (int t = 0; t < 4; ++t) {
                int off = kc * 4096 + (wm + t * 16 + l15) * 32 + quad * 8;
                f16x8 a1 = *(const f16x8*)&As1[off];
                f16x8 a2 = *(const f16x8*)&As2[off];
                af[t] = a1 + a2;
            }
#pragma unroll
            for (int t = 0; t < 2; ++t)
                bf[t] = *(const f16x8*)&Bs[kc * 2048 + (wn + t * 16 + l15) * 32 + quad * 8];
#pragma unroll
            for (int im = 0; im < 4; ++im)
#pragma unroll
                for (int in = 0; in < 2; ++in)
                    acc[im][in] = __builtin_amdgcn_mfma_f32_16x16x32_f16(af[im], bf[in], acc[im][in], 0, 0, 0);
        }
    }
#pragma unroll
    for (int im = 0; im < 4; ++im)
#pragma unroll
        for (int in = 0; in < 2; ++in)
#pragma unroll
            for (int r = 0; r < 4; ++r) {
                int row = tm + wm + im * 16 + quad * 4 + r;
                int col = tn + wn + in * 16 + l15;
                C[(size_t)row * DIM + col] = acc[im][in][r] + bias[col];
            }
}

extern "C" void kernel_launch(void* const* d_in, const int* in_sizes, int n_in,
                              void* d_out, int out_size, void* d_ws, size_t ws_size,
                              hipStream_t stream) {
    const float* x  = (const float*)d_in[0];
    const float* Wq = (const float*)d_in[1];
    const float* bq = (const float*)d_in[2];
    const float* Wk = (const float*)d_in[3];
    const float* bk = (const float*)d_in[4];
    const float* Wv = (const float*)d_in[5];
    const float* bv = (const float*)d_in[6];
    const float* Wo = (const float*)d_in[7];
    const float* bo = (const float*)d_in[8];
    float* out = (float*)d_out;

    char* ws = (char*)d_ws;
    const size_t MB = 1u << 20;
    __bf16*    xb  = (__bf16*)(ws);              // 8 MB
    __bf16*    Wqb = (__bf16*)(ws + 8 * MB);
    __bf16*    Wkb = (__bf16*)(ws + 10 * MB);
    __bf16*    Wvb = (__bf16*)(ws + 12 * MB);
    _Float16*  Wof = (_Float16*)(ws + 14 * MB);
    __bf16*    Qb  = (__bf16*)(ws + 16 * MB);    // 8 MB
    __bf16*    Kb  = (__bf16*)(ws + 24 * MB);    // 8 MB
    _Float16*  VtH = (_Float16*)(ws + 32 * MB);  // 8 MB
    __bf16*    rd  = (__bf16*)(ws + 40 * MB);    // 16 MB
    _Float16*  AO1 = (_Float16*)(ws + 56 * MB);  // 8 MB
    _Float16*  AO2 = (_Float16*)(ws + 64 * MB);  // 8 MB (total 72 MB)

    cast_f32_bf16<<<4096, 256, 0, stream>>>(x, xb, MTOT * DIM);
    cast_w4<<<dim3(1024, 4), 256, 0, stream>>>(Wq, Wk, Wv, Wo, Wqb, Wkb, Wvb, Wof, DIM * DIM);

    qkv_gemm<<<dim3(24, 32), 256, 0, stream>>>(xb, Wqb, Wkb, Wvb, bq, bk, bv, Qb, Kb, VtH);

    den6<<<dim3(S_LEN / 64, S_LEN / 64, 2), 256, 0, stream>>>(Qb, Kb, rd);

    attn6<<<dim3((S_LEN / 128) * 2, NH, 2), 256, 0, stream>>>(Qb, Kb, VtH, rd, AO1, AO2);

    gemm_out2<<<dim3(DIM / 64, MTOT / 128), 256, 0, stream>>>(AO1, AO2, Wof, bo, out);
}

// Round 7
// 272.603 us; speedup vs baseline: 1.0613x; 1.0180x over previous
//
#include <hip/hip_runtime.h>
#include <hip/hip_bf16.h>
#include <cstdint>
#include <cstddef>

// B=2, S=2048, D=1024, H=16, HD=64.  softmax over HEAD axis.
// v7: 512-thread / 8-wave attn+den blocks (same LDS footprint -> 32 waves/CU),
// single-barrier dbuf k-loops, all casts fused into one dispatch.

typedef __bf16 bf16x8 __attribute__((ext_vector_type(8)));
typedef __bf16 bf16x4 __attribute__((ext_vector_type(4)));
typedef _Float16 f16x4 __attribute__((ext_vector_type(4)));
typedef _Float16 f16x8 __attribute__((ext_vector_type(8)));
typedef float floatx4 __attribute__((ext_vector_type(4)));

#define S_LEN 2048
#define DIM 1024
#define NH 16
#define HD 64
#define MTOT 4096  // B * S
#define C_EXP 0.1803368801111244f  // log2(e)/8

__device__ __forceinline__ float fast_exp2(float x) { return __builtin_amdgcn_exp2f(x); }

__device__ __forceinline__ void g2l16(const void* g, void* l) {
    __builtin_amdgcn_global_load_lds(
        (const __attribute__((address_space(1))) void*)g,
        (__attribute__((address_space(3))) void*)l, 16, 0, 0);
}

// ---------------- fused cast: x -> bf16, Wq/Wk/Wv -> bf16, Wo -> f16 ----------------
// grid.x = 4096 (x) + 4*1024 (weights) = 8192 blocks, 256 thr, 4 elems/thr.
__global__ void cast_all(const float* __restrict__ x,
                         const float* __restrict__ w0, const float* __restrict__ w1,
                         const float* __restrict__ w2, const float* __restrict__ w3,
                         __bf16* __restrict__ xb,
                         __bf16* __restrict__ o0, __bf16* __restrict__ o1,
                         __bf16* __restrict__ o2, _Float16* __restrict__ o3) {
    int bid = blockIdx.x;
    if (bid < 4096) {
        int i = (bid * 256 + threadIdx.x) * 4;
        float4 v = *(const float4*)&x[i];
        bf16x4 o;
        o.x = (__bf16)v.x; o.y = (__bf16)v.y; o.z = (__bf16)v.z; o.w = (__bf16)v.w;
        *(bf16x4*)&xb[i] = o;
        return;
    }
    bid -= 4096;
    int wi = bid >> 10;
    int i = ((bid & 1023) * 256 + threadIdx.x) * 4;
    if (wi == 3) {
        float4 v = *(const float4*)&w3[i];
        f16x4 o;
        o[0] = (_Float16)v.x; o[1] = (_Float16)v.y; o[2] = (_Float16)v.z; o[3] = (_Float16)v.w;
        *(f16x4*)&o3[i] = o;
        return;
    }
    const float* s = (wi == 0) ? w0 : (wi == 1) ? w1 : w2;
    __bf16* d = (wi == 0) ? o0 : (wi == 1) ? o1 : o2;
    float4 v = *(const float4*)&s[i];
    bf16x4 o;
    o.x = (__bf16)v.x; o.y = (__bf16)v.y; o.z = (__bf16)v.z; o.w = (__bf16)v.w;
    *(bf16x4*)&d[i] = o;
}

// ---------------- fused QKV projection GEMM (m97 structure) ----------------
__global__ __launch_bounds__(256, 2) void qkv_gemm(const __bf16* __restrict__ A,
                                                   const __bf16* __restrict__ Wq,
                                                   const __bf16* __restrict__ Wk,
                                                   const __bf16* __restrict__ Wv,
                                                   const float* __restrict__ bq,
                                                   const float* __restrict__ bk,
                                                   const float* __restrict__ bv,
                                                   __bf16* __restrict__ Qo,
                                                   __bf16* __restrict__ Ko,
                                                   _Float16* __restrict__ Vt) {
    const int tng = blockIdx.x * 128, tm = blockIdx.y * 128;
    const int wsel = tng >> 10, tn = tng & 1023;
    const __bf16* W = (wsel == 0) ? Wq : (wsel == 1) ? Wk : Wv;
    const float* bias = (wsel == 0) ? bq : (wsel == 1) ? bk : bv;
    __shared__ __bf16 As[128 * 32];
    __shared__ __bf16 Bs[128 * 32];
    const int tid = threadIdx.x, wid = tid >> 6, lane = tid & 63;
    const int l15 = lane & 15, quad = lane >> 4;
    const int wm = (wid >> 1) * 64, wn = (wid & 1) * 64;
    floatx4 acc[4][4] = {};
    for (int k0 = 0; k0 < DIM; k0 += 32) {
        __syncthreads();
#pragma unroll
        for (int i = 0; i < 2; ++i) {
            int slot = i * 256 + tid;
            int r = slot >> 2, c8 = (slot & 3) * 8;
            g2l16(&A[(size_t)(tm + r) * DIM + k0 + c8], &As[slot * 8]);
            g2l16(&W[(size_t)(tn + r) * DIM + k0 + c8], &Bs[slot * 8]);
        }
        __syncthreads();
        bf16x8 af[4], bf[4];
#pragma unroll
        for (int t = 0; t < 4; ++t) {
            af[t] = *(const bf16x8*)&As[(wm + t * 16 + l15) * 32 + quad * 8];
            bf[t] = *(const bf16x8*)&Bs[(wn + t * 16 + l15) * 32 + quad * 8];
        }
#pragma unroll
        for (int im = 0; im < 4; ++im)
#pragma unroll
            for (int in = 0; in < 4; ++in)
                acc[im][in] = __builtin_amdgcn_mfma_f32_16x16x32_bf16(af[im], bf[in], acc[im][in], 0, 0, 0);
    }
    if (wsel < 2) {
        __bf16* O = wsel ? Ko : Qo;
#pragma unroll
        for (int im = 0; im < 4; ++im)
#pragma unroll
            for (int in = 0; in < 4; ++in)
#pragma unroll
                for (int r = 0; r < 4; ++r) {
                    int row = tm + wm + im * 16 + quad * 4 + r;
                    int col = tn + wn + in * 16 + l15;
                    O[(size_t)row * DIM + col] = (__bf16)(acc[im][in][r] + bias[col]);
                }
    } else {
#pragma unroll
        for (int im = 0; im < 4; ++im)
#pragma unroll
            for (int in = 0; in < 4; ++in) {
                int cv = tn + wn + in * 16 + l15;
                int row4 = tm + wm + im * 16 + quad * 4;
                float bv_ = bias[cv];
                f16x4 o;
#pragma unroll
                for (int r = 0; r < 4; ++r) o[r] = (_Float16)(acc[im][in][r] + bv_);
                *(f16x4*)&Vt[(size_t)cv * MTOT + row4] = o;
            }
    }
}

// ---------------- pass 1: rd = 1/sum_h exp(s/8), 8-wave blocks ----------------
// block 128q x 64k, 2 heads per dbuf iter. grid (32,16,2)=1024, 4 blocks/CU.
__global__ __launch_bounds__(512, 8) void den7(const __bf16* __restrict__ Q,
                                               const __bf16* __restrict__ Km,
                                               __bf16* __restrict__ rd) {
    const int kt = blockIdx.x * 64, qt = blockIdx.y * 128, b = blockIdx.z;
    __shared__ __bf16 Ks[2][2 * 2 * 64 * 32];  // 2 bufs x 16 KB
    const int tid = threadIdx.x, wid = tid >> 6, lane = tid & 63;
    const int l15 = lane & 15, quad = lane >> 4;
    const int wq = wid * 16;
    floatx4 dsum[4] = {};
    const size_t qrow = (size_t)(b * S_LEN + qt + wq + l15) * DIM;
    const size_t kbase = (size_t)(b * S_LEN + kt) * DIM;

    // prologue: stage hh=0 into buf 0 (2 g2l16 per thread)
#pragma unroll
    for (int i = 0; i < 2; ++i) {
        int slot = i * 512 + tid;  // 0..1023
        int hs = slot >> 9, rem = slot & 511;
        int p = rem >> 8, rem2 = rem & 255;
        int r = rem2 >> 2, c8 = (rem2 & 3) * 8;
        g2l16(&Km[kbase + (size_t)r * DIM + hs * HD + p * 32 + c8], &Ks[0][slot * 8]);
    }
    for (int hh = 0; hh < 8; ++hh) {
        const int cur = hh & 1, nxt = cur ^ 1;
        __syncthreads();
        bf16x8 af[2][2];
#pragma unroll
        for (int hs = 0; hs < 2; ++hs) {
            af[hs][0] = *(const bf16x8*)&Q[qrow + (hh * 2 + hs) * HD + quad * 8];
            af[hs][1] = *(const bf16x8*)&Q[qrow + (hh * 2 + hs) * HD + 32 + quad * 8];
        }
        if (hh + 1 < 8) {
#pragma unroll
            for (int i = 0; i < 2; ++i) {
                int slot = i * 512 + tid;
                int hs = slot >> 9, rem = slot & 511;
                int p = rem >> 8, rem2 = rem & 255;
                int r = rem2 >> 2, c8 = (rem2 & 3) * 8;
                g2l16(&Km[kbase + (size_t)r * DIM + ((hh + 1) * 2 + hs) * HD + p * 32 + c8],
                      &Ks[nxt][slot * 8]);
            }
        }
#pragma unroll
        for (int hs = 0; hs < 2; ++hs) {
#pragma unroll
            for (int n = 0; n < 4; ++n) {
                bf16x8 b0 = *(const bf16x8*)&Ks[cur][hs * 4096 + (n * 16 + l15) * 32 + quad * 8];
                bf16x8 b1 = *(const bf16x8*)&Ks[cur][hs * 4096 + 2048 + (n * 16 + l15) * 32 + quad * 8];
                floatx4 acc = {};
                acc = __builtin_amdgcn_mfma_f32_16x16x32_bf16(af[hs][0], b0, acc, 0, 0, 0);
                acc = __builtin_amdgcn_mfma_f32_16x16x32_bf16(af[hs][1], b1, acc, 0, 0, 0);
#pragma unroll
                for (int r = 0; r < 4; ++r) dsum[n][r] += fast_exp2(acc[r] * C_EXP);
            }
        }
    }
#pragma unroll
    for (int n = 0; n < 4; ++n)
#pragma unroll
        for (int r = 0; r < 4; ++r) {
            int q = qt + wq + quad * 4 + r;
            int k = kt + n * 16 + l15;
            rd[(size_t)(b * S_LEN + q) * S_LEN + k] = (__bf16)(1.0f / dsum[n][r]);
        }
}

// ---------------- pass 2: partial AO, 8-wave blocks, dbuf single-barrier ----------------
// block 128q, k-tile 64, k-split 2 -> grid (32,16,2)=1024, 4 blocks/CU, 32 waves/CU.
__global__ __launch_bounds__(512, 8) void attn7(const __bf16* __restrict__ Q,
                                                const __bf16* __restrict__ Km,
                                                const _Float16* __restrict__ Vt,
                                                const __bf16* __restrict__ rd,
                                                _Float16* __restrict__ AO1,
                                                _Float16* __restrict__ AO2) {
    const int qt = (blockIdx.x >> 1) * 128, ks = blockIdx.x & 1;
    const int h = blockIdx.y, b = blockIdx.z;
    __shared__ __bf16 Ks[2][2 * 64 * 32];   // 2 bufs x 8 KB, panels [p][tok][32]
    __shared__ _Float16 Vts[2][64 * 72];    // 2 bufs x 9 KB, padded [d][ktok]
    const int tid = threadIdx.x, wid = tid >> 6, lane = tid & 63;
    const int l15 = lane & 15, quad = lane >> 4;
    const int wq = wid * 16;
    const size_t qrow = (size_t)(b * S_LEN + qt + wq + l15) * DIM + h * HD;
    bf16x8 qf0 = *(const bf16x8*)&Q[qrow + quad * 8];
    bf16x8 qf1 = *(const bf16x8*)&Q[qrow + 32 + quad * 8];
    const __bf16* rdrow = &rd[(size_t)(b * S_LEN + qt + wq + l15) * S_LEN];
    floatx4 oacc[4] = {};
    const int kt0 = ks * (S_LEN / 2);
    const size_t kdim = (size_t)b * S_LEN * DIM;

    // prologue: stage kt0 into buf 0 (1 g2l16 + 1 V f16x8 per thread)
    {
        int vr = tid >> 3, vc = (tid & 7) * 8;
        f16x8 vtmp = *(const f16x8*)&Vt[(size_t)(h * HD + vr) * MTOT + b * S_LEN + kt0 + vc];
        int p = tid >> 8, rem = tid & 255;
        int r = rem >> 2, c8 = (rem & 3) * 8;
        g2l16(&Km[kdim + (size_t)(kt0 + r) * DIM + h * HD + p * 32 + c8], &Ks[0][tid * 8]);
        *(f16x8*)&Vts[0][vr * 72 + vc] = vtmp;
    }
    for (int it = 0; it < 16; ++it) {
        const int cur = it & 1, nxt = cur ^ 1;
        const int kt = kt0 + it * 64;
        __syncthreads();
        // stage next tile (flies during compute of cur)
        if (it + 1 < 16) {
            const int ktn = kt + 64;
            int vr = tid >> 3, vc = (tid & 7) * 8;
            f16x8 vtmp = *(const f16x8*)&Vt[(size_t)(h * HD + vr) * MTOT + b * S_LEN + ktn + vc];
            int p = tid >> 8, rem = tid & 255;
            int r = rem >> 2, c8 = (rem & 3) * 8;
            g2l16(&Km[kdim + (size_t)(ktn + r) * DIM + h * HD + p * 32 + c8], &Ks[nxt][tid * 8]);
            *(f16x8*)&Vts[nxt][vr * 72 + vc] = vtmp;
        }
        // compute current tile
#pragma unroll
        for (int mp = 0; mp < 4; ++mp) {
            bf16x8 kf0 = *(const bf16x8*)&Ks[cur][(mp * 16 + l15) * 32 + quad * 8];
            bf16x8 kf1 = *(const bf16x8*)&Ks[cur][2048 + (mp * 16 + l15) * 32 + quad * 8];
            floatx4 s = {};
            s = __builtin_amdgcn_mfma_f32_16x16x32_bf16(kf0, qf0, s, 0, 0, 0);
            s = __builtin_amdgcn_mfma_f32_16x16x32_bf16(kf1, qf1, s, 0, 0, 0);
            bf16x4 rv = *(const bf16x4*)&rdrow[kt + mp * 16 + quad * 4];
            f16x4 pa;
#pragma unroll
            for (int r = 0; r < 4; ++r)
                pa[r] = (_Float16)(fast_exp2(s[r] * C_EXP) * (float)rv[r]);
#pragma unroll
            for (int n = 0; n < 4; ++n) {
                f16x4 vb = *(const f16x4*)&Vts[cur][(n * 16 + l15) * 72 + mp * 16 + quad * 4];
                oacc[n] = __builtin_amdgcn_mfma_f32_16x16x16f16(pa, vb, oacc[n], 0, 0, 0);
            }
        }
    }
    _Float16* AO = ks ? AO2 : AO1;
#pragma unroll
    for (int n = 0; n < 4; ++n)
#pragma unroll
        for (int r = 0; r < 4; ++r) {
            int row = qt + wq + quad * 4 + r;
            int col = h * HD + n * 16 + l15;
            AO[(size_t)(b * S_LEN + row) * DIM + col] = (_Float16)oacc[n][r];
        }
}

// ---------------- output projection: C = (AO1+AO2) @ Wo^T + bo ----------------
__global__ __launch_bounds__(256, 2) void gemm_out2(const _Float16* __restrict__ A1,
                                                    const _Float16* __restrict__ A2,
                                                    const _Float16* __restrict__ Bw,
                                                    const float* __restrict__ bias,
                                                    float* __restrict__ C) {
    const int tm = blockIdx.y * 128, tn = blockIdx.x * 64;
    __shared__ _Float16 As1[2 * 128 * 32];
    __shared__ _Float16 As2[2 * 128 * 32];
    __shared__ _Float16 Bs[2 * 64 * 32];
    const int tid = threadIdx.x, wid = tid >> 6, lane = tid & 63;
    const int l15 = lane & 15, quad = lane >> 4;
    const int wm = (wid >> 1) * 64, wn = (wid & 1) * 32;
    floatx4 acc[4][2] = {};
    for (int k0 = 0; k0 < DIM; k0 += 64) {
        __syncthreads();
#pragma unroll
        for (int i = 0; i < 4; ++i) {
            int slot = i * 256 + tid;
            int p = slot >> 9, rem = slot & 511;
            int r = rem >> 2, c8 = (rem & 3) * 8;
            size_t ga = (size_t)(tm + r) * DIM + k0 + p * 32 + c8;
            g2l16(&A1[ga], &As1[slot * 8]);
            g2l16(&A2[ga], &As2[slot * 8]);
        }
#pragma unroll
        for (int i = 0; i < 2; ++i) {
            int slot = i * 256 + tid;
            int p = slot >> 8, rem = slot & 255;
            int r = rem >> 2, c8 = (rem & 3) * 8;
            g2l16(&Bw[(size_t)(tn + r) * DIM + k0 + p * 32 + c8], &Bs[slot * 8]);
        }
        __syncthreads();
#pragma unroll
        for (int kc = 0; kc < 2; ++kc) {
            f16x8 af[4], bf[2];
#pragma unroll
            for (int t = 0; t < 4; ++t) {
                int off = kc * 4096 + (wm + t * 16 + l15) * 32 + quad * 8;
                f16x8 a1 = *(const f16x8*)&As1[off];
                f16x8 a2 = *(const f16x8*)&As2[off];
                af[t] = a1 + a2;
            }
#pragma unroll
            for (int t = 0; t < 2; ++t)
                bf[t] = *(const f16x8*)&Bs[kc * 2048 + (wn + t * 16 + l15) * 32 + quad * 8];
#pragma unroll
            for (int im = 0; im < 4; ++im)
#pragma unroll
                for (int in = 0; in < 2; ++in)
                    acc[im][in] = __builtin_amdgcn_mfma_f32_16x16x32_f16(af[im], bf[in], acc[im][in], 0, 0, 0);
        }
    }
#pragma unroll
    for (int im = 0; im < 4; ++im)
#pragma unroll
        for (int in = 0; in < 2; ++in)
#pragma unroll
            for (int r = 0; r < 4; ++r) {
                int row = tm + wm + im * 16 + quad * 4 + r;
                int col = tn + wn + in * 16 + l15;
                C[(size_t)row * DIM + col] = acc[im][in][r] + bias[col];
            }
}

extern "C" void kernel_launch(void* const* d_in, const int* in_sizes, int n_in,
                              void* d_out, int out_size, void* d_ws, size_t ws_size,
                              hipStream_t stream) {
    const float* x  = (const float*)d_in[0];
    const float* Wq = (const float*)d_in[1];
    const float* bq = (const float*)d_in[2];
    const float* Wk = (const float*)d_in[3];
    const float* bk = (const float*)d_in[4];
    const float* Wv = (const float*)d_in[5];
    const float* bv = (const float*)d_in[6];
    const float* Wo = (const float*)d_in[7];
    const float* bo = (const float*)d_in[8];
    float* out = (float*)d_out;

    char* ws = (char*)d_ws;
    const size_t MB = 1u << 20;
    __bf16*    xb  = (__bf16*)(ws);              // 8 MB
    __bf16*    Wqb = (__bf16*)(ws + 8 * MB);
    __bf16*    Wkb = (__bf16*)(ws + 10 * MB);
    __bf16*    Wvb = (__bf16*)(ws + 12 * MB);
    _Float16*  Wof = (_Float16*)(ws + 14 * MB);
    __bf16*    Qb  = (__bf16*)(ws + 16 * MB);    // 8 MB
    __bf16*    Kb  = (__bf16*)(ws + 24 * MB);    // 8 MB
    _Float16*  VtH = (_Float16*)(ws + 32 * MB);  // 8 MB
    __bf16*    rd  = (__bf16*)(ws + 40 * MB);    // 16 MB
    _Float16*  AO1 = (_Float16*)(ws + 56 * MB);  // 8 MB
    _Float16*  AO2 = (_Float16*)(ws + 64 * MB);  // 8 MB (total 72 MB)

    cast_all<<<8192, 256, 0, stream>>>(x, Wq, Wk, Wv, Wo, xb, Wqb, Wkb, Wvb, Wof);

    qkv_gemm<<<dim3(24, 32), 256, 0, stream>>>(xb, Wqb, Wkb, Wvb, bq, bk, bv, Qb, Kb, VtH);

    den7<<<dim3(S_LEN / 64, S_LEN / 128, 2), 512, 0, stream>>>(Qb, Kb, rd);

    attn7<<<dim3((S_LEN / 128) * 2, NH, 2), 512, 0, stream>>>(Qb, Kb, VtH, rd, AO1, AO2);

    gemm_out2<<<dim3(DIM / 64, MTOT / 128), 256, 0, stream>>>(AO1, AO2, Wof, bo, out);
}

// Round 9
// 269.209 us; speedup vs baseline: 1.0747x; 1.0126x over previous
//
#include <hip/hip_runtime.h>
#include <hip/hip_bf16.h>
#include <cstdint>
#include <cstddef>

// B=2, S=2048, D=1024, H=16, HD=64.  softmax over HEAD axis.
// v8b: v8 with cvt_pkrtz result bit_cast to f16x2 (clang type mismatch fix).
// (1) V ds_write moved AFTER compute, (2) VALU-diet exp path (f16 rd, pk ops),
// (3) rv loads hoisted before staging.

typedef __bf16 bf16x8 __attribute__((ext_vector_type(8)));
typedef __bf16 bf16x4 __attribute__((ext_vector_type(4)));
typedef _Float16 f16x2 __attribute__((ext_vector_type(2)));
typedef _Float16 f16x4 __attribute__((ext_vector_type(4)));
typedef _Float16 f16x8 __attribute__((ext_vector_type(8)));
typedef float floatx4 __attribute__((ext_vector_type(4)));

#define S_LEN 2048
#define DIM 1024
#define NH 16
#define HD 64
#define MTOT 4096  // B * S
#define C_EXP 0.1803368801111244f  // log2(e)/8

__device__ __forceinline__ float fast_exp2(float x) { return __builtin_amdgcn_exp2f(x); }

__device__ __forceinline__ f16x2 pk_cvt(float a, float b) {
    return __builtin_bit_cast(f16x2, __builtin_amdgcn_cvt_pkrtz(a, b));
}

__device__ __forceinline__ void g2l16(const void* g, void* l) {
    __builtin_amdgcn_global_load_lds(
        (const __attribute__((address_space(1))) void*)g,
        (__attribute__((address_space(3))) void*)l, 16, 0, 0);
}

// ---------------- fused cast: x -> bf16, Wq/Wk/Wv -> bf16, Wo -> f16 ----------------
__global__ void cast_all(const float* __restrict__ x,
                         const float* __restrict__ w0, const float* __restrict__ w1,
                         const float* __restrict__ w2, const float* __restrict__ w3,
                         __bf16* __restrict__ xb,
                         __bf16* __restrict__ o0, __bf16* __restrict__ o1,
                         __bf16* __restrict__ o2, _Float16* __restrict__ o3) {
    int bid = blockIdx.x;
    if (bid < 4096) {
        int i = (bid * 256 + threadIdx.x) * 4;
        float4 v = *(const float4*)&x[i];
        bf16x4 o;
        o.x = (__bf16)v.x; o.y = (__bf16)v.y; o.z = (__bf16)v.z; o.w = (__bf16)v.w;
        *(bf16x4*)&xb[i] = o;
        return;
    }
    bid -= 4096;
    int wi = bid >> 10;
    int i = ((bid & 1023) * 256 + threadIdx.x) * 4;
    if (wi == 3) {
        float4 v = *(const float4*)&w3[i];
        f16x4 o;
        o[0] = (_Float16)v.x; o[1] = (_Float16)v.y; o[2] = (_Float16)v.z; o[3] = (_Float16)v.w;
        *(f16x4*)&o3[i] = o;
        return;
    }
    const float* s = (wi == 0) ? w0 : (wi == 1) ? w1 : w2;
    __bf16* d = (wi == 0) ? o0 : (wi == 1) ? o1 : o2;
    float4 v = *(const float4*)&s[i];
    bf16x4 o;
    o.x = (__bf16)v.x; o.y = (__bf16)v.y; o.z = (__bf16)v.z; o.w = (__bf16)v.w;
    *(bf16x4*)&d[i] = o;
}

// ---------------- fused QKV projection GEMM (m97 structure) ----------------
__global__ __launch_bounds__(256, 2) void qkv_gemm(const __bf16* __restrict__ A,
                                                   const __bf16* __restrict__ Wq,
                                                   const __bf16* __restrict__ Wk,
                                                   const __bf16* __restrict__ Wv,
                                                   const float* __restrict__ bq,
                                                   const float* __restrict__ bk,
                                                   const float* __restrict__ bv,
                                                   __bf16* __restrict__ Qo,
                                                   __bf16* __restrict__ Ko,
                                                   _Float16* __restrict__ Vt) {
    const int tng = blockIdx.x * 128, tm = blockIdx.y * 128;
    const int wsel = tng >> 10, tn = tng & 1023;
    const __bf16* W = (wsel == 0) ? Wq : (wsel == 1) ? Wk : Wv;
    const float* bias = (wsel == 0) ? bq : (wsel == 1) ? bk : bv;
    __shared__ __bf16 As[128 * 32];
    __shared__ __bf16 Bs[128 * 32];
    const int tid = threadIdx.x, wid = tid >> 6, lane = tid & 63;
    const int l15 = lane & 15, quad = lane >> 4;
    const int wm = (wid >> 1) * 64, wn = (wid & 1) * 64;
    floatx4 acc[4][4] = {};
    for (int k0 = 0; k0 < DIM; k0 += 32) {
        __syncthreads();
#pragma unroll
        for (int i = 0; i < 2; ++i) {
            int slot = i * 256 + tid;
            int r = slot >> 2, c8 = (slot & 3) * 8;
            g2l16(&A[(size_t)(tm + r) * DIM + k0 + c8], &As[slot * 8]);
            g2l16(&W[(size_t)(tn + r) * DIM + k0 + c8], &Bs[slot * 8]);
        }
        __syncthreads();
        bf16x8 af[4], bf[4];
#pragma unroll
        for (int t = 0; t < 4; ++t) {
            af[t] = *(const bf16x8*)&As[(wm + t * 16 + l15) * 32 + quad * 8];
            bf[t] = *(const bf16x8*)&Bs[(wn + t * 16 + l15) * 32 + quad * 8];
        }
#pragma unroll
        for (int im = 0; im < 4; ++im)
#pragma unroll
            for (int in = 0; in < 4; ++in)
                acc[im][in] = __builtin_amdgcn_mfma_f32_16x16x32_bf16(af[im], bf[in], acc[im][in], 0, 0, 0);
    }
    if (wsel < 2) {
        __bf16* O = wsel ? Ko : Qo;
#pragma unroll
        for (int im = 0; im < 4; ++im)
#pragma unroll
            for (int in = 0; in < 4; ++in)
#pragma unroll
                for (int r = 0; r < 4; ++r) {
                    int row = tm + wm + im * 16 + quad * 4 + r;
                    int col = tn + wn + in * 16 + l15;
                    O[(size_t)row * DIM + col] = (__bf16)(acc[im][in][r] + bias[col]);
                }
    } else {
#pragma unroll
        for (int im = 0; im < 4; ++im)
#pragma unroll
            for (int in = 0; in < 4; ++in) {
                int cv = tn + wn + in * 16 + l15;
                int row4 = tm + wm + im * 16 + quad * 4;
                float bv_ = bias[cv];
                f16x4 o;
#pragma unroll
                for (int r = 0; r < 4; ++r) o[r] = (_Float16)(acc[im][in][r] + bv_);
                *(f16x4*)&Vt[(size_t)cv * MTOT + row4] = o;
            }
    }
}

// ---------------- pass 1: rd = 1/sum_h exp(s/8)  (f16 out), 8-wave blocks ----------------
__global__ __launch_bounds__(512, 8) void den8(const __bf16* __restrict__ Q,
                                               const __bf16* __restrict__ Km,
                                               _Float16* __restrict__ rd) {
    const int kt = blockIdx.x * 64, qt = blockIdx.y * 128, b = blockIdx.z;
    __shared__ __bf16 Ks[2][2 * 2 * 64 * 32];  // 2 bufs x 16 KB
    const int tid = threadIdx.x, wid = tid >> 6, lane = tid & 63;
    const int l15 = lane & 15, quad = lane >> 4;
    const int wq = wid * 16;
    floatx4 dsum[4] = {};
    const size_t qrow = (size_t)(b * S_LEN + qt + wq + l15) * DIM;
    const size_t kbase = (size_t)(b * S_LEN + kt) * DIM;

#pragma unroll
    for (int i = 0; i < 2; ++i) {
        int slot = i * 512 + tid;
        int hs = slot >> 9, rem = slot & 511;
        int p = rem >> 8, rem2 = rem & 255;
        int r = rem2 >> 2, c8 = (rem2 & 3) * 8;
        g2l16(&Km[kbase + (size_t)r * DIM + hs * HD + p * 32 + c8], &Ks[0][slot * 8]);
    }
    for (int hh = 0; hh < 8; ++hh) {
        const int cur = hh & 1, nxt = cur ^ 1;
        __syncthreads();
        bf16x8 af[2][2];
#pragma unroll
        for (int hs = 0; hs < 2; ++hs) {
            af[hs][0] = *(const bf16x8*)&Q[qrow + (hh * 2 + hs) * HD + quad * 8];
            af[hs][1] = *(const bf16x8*)&Q[qrow + (hh * 2 + hs) * HD + 32 + quad * 8];
        }
        if (hh + 1 < 8) {
#pragma unroll
            for (int i = 0; i < 2; ++i) {
                int slot = i * 512 + tid;
                int hs = slot >> 9, rem = slot & 511;
                int p = rem >> 8, rem2 = rem & 255;
                int r = rem2 >> 2, c8 = (rem2 & 3) * 8;
                g2l16(&Km[kbase + (size_t)r * DIM + ((hh + 1) * 2 + hs) * HD + p * 32 + c8],
                      &Ks[nxt][slot * 8]);
            }
        }
#pragma unroll
        for (int hs = 0; hs < 2; ++hs) {
#pragma unroll
            for (int n = 0; n < 4; ++n) {
                bf16x8 b0 = *(const bf16x8*)&Ks[cur][hs * 4096 + (n * 16 + l15) * 32 + quad * 8];
                bf16x8 b1 = *(const bf16x8*)&Ks[cur][hs * 4096 + 2048 + (n * 16 + l15) * 32 + quad * 8];
                floatx4 acc = {};
                acc = __builtin_amdgcn_mfma_f32_16x16x32_bf16(af[hs][0], b0, acc, 0, 0, 0);
                acc = __builtin_amdgcn_mfma_f32_16x16x32_bf16(af[hs][1], b1, acc, 0, 0, 0);
                floatx4 sc = acc * C_EXP;
                floatx4 e;
#pragma unroll
                for (int r = 0; r < 4; ++r) e[r] = fast_exp2(sc[r]);
                dsum[n] += e;
            }
        }
    }
#pragma unroll
    for (int n = 0; n < 4; ++n)
#pragma unroll
        for (int r = 0; r < 4; ++r) {
            int q = qt + wq + quad * 4 + r;
            int k = kt + n * 16 + l15;
            rd[(size_t)(b * S_LEN + q) * S_LEN + k] = (_Float16)(1.0f / dsum[n][r]);
        }
}

// ---------------- pass 2: partial AO, 8-wave blocks, post-compute V commit ----------------
__global__ __launch_bounds__(512, 8) void attn8(const __bf16* __restrict__ Q,
                                                const __bf16* __restrict__ Km,
                                                const _Float16* __restrict__ Vt,
                                                const _Float16* __restrict__ rd,
                                                _Float16* __restrict__ AO1,
                                                _Float16* __restrict__ AO2) {
    const int qt = (blockIdx.x >> 1) * 128, ks = blockIdx.x & 1;
    const int h = blockIdx.y, b = blockIdx.z;
    __shared__ __bf16 Ks[2][2 * 64 * 32];   // 2 bufs x 8 KB, panels [p][tok][32]
    __shared__ _Float16 Vts[2][64 * 72];    // 2 bufs x 9 KB, padded [d][ktok]
    const int tid = threadIdx.x, wid = tid >> 6, lane = tid & 63;
    const int l15 = lane & 15, quad = lane >> 4;
    const int wq = wid * 16;
    const size_t qrow = (size_t)(b * S_LEN + qt + wq + l15) * DIM + h * HD;
    bf16x8 qf0 = *(const bf16x8*)&Q[qrow + quad * 8];
    bf16x8 qf1 = *(const bf16x8*)&Q[qrow + 32 + quad * 8];
    const _Float16* rdrow = &rd[(size_t)(b * S_LEN + qt + wq + l15) * S_LEN];
    floatx4 oacc[4] = {};
    const int kt0 = ks * (S_LEN / 2);
    const size_t kdim = (size_t)b * S_LEN * DIM;
    const int vr = tid >> 3, vc = (tid & 7) * 8;
    const int sp = tid >> 8, srem = tid & 255;
    const int sr = srem >> 2, sc8 = (srem & 3) * 8;

    // prologue: stage kt0 into buf 0
    {
        f16x8 vtmp = *(const f16x8*)&Vt[(size_t)(h * HD + vr) * MTOT + b * S_LEN + kt0 + vc];
        g2l16(&Km[kdim + (size_t)(kt0 + sr) * DIM + h * HD + sp * 32 + sc8], &Ks[0][tid * 8]);
        *(f16x8*)&Vts[0][vr * 72 + vc] = vtmp;
    }
    for (int it = 0; it < 16; ++it) {
        const int cur = it & 1, nxt = cur ^ 1;
        const int kt = kt0 + it * 64;
        __syncthreads();
        // rv for this iter (issued first -> oldest in vmcnt FIFO, covered by QK MFMA)
        f16x4 rv[4];
#pragma unroll
        for (int mp = 0; mp < 4; ++mp)
            rv[mp] = *(const f16x4*)&rdrow[kt + mp * 16 + quad * 4];
        // issue next tile's loads (V kept in regs; committed to LDS after compute)
        f16x8 vtmp;
        const bool has_next = (it + 1 < 16);
        if (has_next) {
            const int ktn = kt + 64;
            vtmp = *(const f16x8*)&Vt[(size_t)(h * HD + vr) * MTOT + b * S_LEN + ktn + vc];
            g2l16(&Km[kdim + (size_t)(ktn + sr) * DIM + h * HD + sp * 32 + sc8], &Ks[nxt][tid * 8]);
        }
        // compute current tile
#pragma unroll
        for (int mp = 0; mp < 4; ++mp) {
            bf16x8 kf0 = *(const bf16x8*)&Ks[cur][(mp * 16 + l15) * 32 + quad * 8];
            bf16x8 kf1 = *(const bf16x8*)&Ks[cur][2048 + (mp * 16 + l15) * 32 + quad * 8];
            floatx4 s = {};
            s = __builtin_amdgcn_mfma_f32_16x16x32_bf16(kf0, qf0, s, 0, 0, 0);
            s = __builtin_amdgcn_mfma_f32_16x16x32_bf16(kf1, qf1, s, 0, 0, 0);
            floatx4 sc = s * C_EXP;
            f16x2 p01 = pk_cvt(fast_exp2(sc[0]), fast_exp2(sc[1]));
            f16x2 p23 = pk_cvt(fast_exp2(sc[2]), fast_exp2(sc[3]));
            f16x4 pa = __builtin_shufflevector(p01, p23, 0, 1, 2, 3);
            pa = pa * rv[mp];  // v_pk_mul_f16 x2
#pragma unroll
            for (int n = 0; n < 4; ++n) {
                f16x4 vb = *(const f16x4*)&Vts[cur][(n * 16 + l15) * 72 + mp * 16 + quad * 4];
                oacc[n] = __builtin_amdgcn_mfma_f32_16x16x16f16(pa, vb, oacc[n], 0, 0, 0);
            }
        }
        // commit next V tile to LDS (vmcnt wait lands here, after compute)
        if (has_next) *(f16x8*)&Vts[nxt][vr * 72 + vc] = vtmp;
    }
    _Float16* AO = ks ? AO2 : AO1;
#pragma unroll
    for (int n = 0; n < 4; ++n)
#pragma unroll
        for (int r = 0; r < 4; ++r) {
            int row = qt + wq + quad * 4 + r;
            int col = h * HD + n * 16 + l15;
            AO[(size_t)(b * S_LEN + row) * DIM + col] = (_Float16)oacc[n][r];
        }
}

// ---------------- output projection: C = (AO1+AO2) @ Wo^T + bo ----------------
__global__ __launch_bounds__(256, 2) void gemm_out2(const _Float16* __restrict__ A1,
                                                    const _Float16* __restrict__ A2,
                                                    const _Float16* __restrict__ Bw,
                                                    const float* __restrict__ bias,
                                                    float* __restrict__ C) {
    const int tm = blockIdx.y * 128, tn = blockIdx.x * 64;
    __shared__ _Float16 As1[2 * 128 * 32];
    __shared__ _Float16 As2[2 * 128 * 32];
    __shared__ _Float16 Bs[2 * 64 * 32];
    const int tid = threadIdx.x, wid = tid >> 6, lane = tid & 63;
    const int l15 = lane & 15, quad = lane >> 4;
    const int wm = (wid >> 1) * 64, wn = (wid & 1) * 32;
    floatx4 acc[4][2] = {};
    for (int k0 = 0; k0 < DIM; k0 += 64) {
        __syncthreads();
#pragma unroll
        for (int i = 0; i < 4; ++i) {
            int slot = i * 256 + tid;
            int p = slot >> 9, rem = slot & 511;
            int r = rem >> 2, c8 = (rem & 3) * 8;
            size_t ga = (size_t)(tm + r) * DIM + k0 + p * 32 + c8;
            g2l16(&A1[ga], &As1[slot * 8]);
            g2l16(&A2[ga], &As2[slot * 8]);
        }
#pragma unroll
        for (int i = 0; i < 2; ++i) {
            int slot = i * 256 + tid;
            int p = slot >> 8, rem = slot & 255;
            int r = rem >> 2, c8 = (rem & 3) * 8;
            g2l16(&Bw[(size_t)(tn + r) * DIM + k0 + p * 32 + c8], &Bs[slot * 8]);
        }
        __syncthreads();
#pragma unroll
        for (int kc = 0; kc < 2; ++kc) {
            f16x8 af[4], bf[2];
#pragma unroll
            for (int t = 0; t < 4; ++t) {
                int off = kc * 4096 + (wm + t * 16 + l15) * 32 + quad * 8;
                f16x8 a1 = *(const f16x8*)&As1[off];
                f16x8 a2 = *(const f16x8*)&As2[off];
                af[t] = a1 + a2;
            }
#pragma unroll
            for (int t = 0; t < 2; ++t)
                bf[t] = *(const f16x8*)&Bs[kc * 2048 + (wn + t * 16 + l15) * 32 + quad * 8];
#pragma unroll
            for (int im = 0; im < 4; ++im)
#pragma unroll
                for (int in = 0; in < 2; ++in)
                    acc[im][in] = __builtin_amdgcn_mfma_f32_16x16x32_f16(af[im], bf[in], acc[im][in], 0, 0, 0);
        }
    }
#pragma unroll
    for (int im = 0; im < 4; ++im)
#pragma unroll
        for (int in = 0; in < 2; ++in)
#pragma unroll
            for (int r = 0; r < 4; ++r) {
                int row = tm + wm + im * 16 + quad * 4 + r;
                int col = tn + wn + in * 16 + l15;
                C[(size_t)row * DIM + col] = acc[im][in][r] + bias[col];
            }
}

extern "C" void kernel_launch(void* const* d_in, const int* in_sizes, int n_in,
                              void* d_out, int out_size, void* d_ws, size_t ws_size,
                              hipStream_t stream) {
    const float* x  = (const float*)d_in[0];
    const float* Wq = (const float*)d_in[1];
    const float* bq = (const float*)d_in[2];
    const float* Wk = (const float*)d_in[3];
    const float* bk = (const float*)d_in[4];
    const float* Wv = (const float*)d_in[5];
    const float* bv = (const float*)d_in[6];
    const float* Wo = (const float*)d_in[7];
    const float* bo = (const float*)d_in[8];
    float* out = (float*)d_out;

    char* ws = (char*)d_ws;
    const size_t MB = 1u << 20;
    __bf16*    xb  = (__bf16*)(ws);              // 8 MB
    __bf16*    Wqb = (__bf16*)(ws + 8 * MB);
    __bf16*    Wkb = (__bf16*)(ws + 10 * MB);
    __bf16*    Wvb = (__bf16*)(ws + 12 * MB);
    _Float16*  Wof = (_Float16*)(ws + 14 * MB);
    __bf16*    Qb  = (__bf16*)(ws + 16 * MB);    // 8 MB
    __bf16*    Kb  = (__bf16*)(ws + 24 * MB);    // 8 MB
    _Float16*  VtH = (_Float16*)(ws + 32 * MB);  // 8 MB
    _Float16*  rd  = (_Float16*)(ws + 40 * MB);  // 8 MB (f16)
    _Float16*  AO1 = (_Float16*)(ws + 56 * MB);  // 8 MB
    _Float16*  AO2 = (_Float16*)(ws + 64 * MB);  // 8 MB

    cast_all<<<8192, 256, 0, stream>>>(x, Wq, Wk, Wv, Wo, xb, Wqb, Wkb, Wvb, Wof);

    qkv_gemm<<<dim3(24, 32), 256, 0, stream>>>(xb, Wqb, Wkb, Wvb, bq, bk, bv, Qb, Kb, VtH);

    den8<<<dim3(S_LEN / 64, S_LEN / 128, 2), 512, 0, stream>>>(Qb, Kb, rd);

    attn8<<<dim3((S_LEN / 128) * 2, NH, 2), 512, 0, stream>>>(Qb, Kb, VtH, rd, AO1, AO2);

    gemm_out2<<<dim3(DIM / 64, MTOT / 128), 256, 0, stream>>>(AO1, AO2, Wof, bo, out);
}